// Round 9
// baseline (726.362 us; speedup 1.0000x reference)
//
#include <hip/hip_runtime.h>
#include <hip/hip_bf16.h>

// Problem constants
#define NB 8
#define NS 8
#define NT 256
#define ND 256
#define NH 8
#define NDK 64
#define NHD 512
#define NL 2
#define NF 256
#define NR 512
#define NM 128
#define NTOK 16384   // B*S*T
#define NROW 1024    // B*M

typedef __attribute__((ext_vector_type(8))) short short8;
typedef __attribute__((ext_vector_type(4))) float f32x4;

// NOTE (R4 post-mortem): do NOT replace f2bf with inline-asm v_cvt_pk_bf16_f32.
// heads_mlp sits at exactly 128 unified regs/wave (launch_bounds 512,4); the
// opaque asm broke the allocator -> 745 B/thread scratch spill, 194->550 us.
__device__ __forceinline__ unsigned short f2bf(float x) {
    unsigned u = __builtin_bit_cast(unsigned, x);
    unsigned r = (u + 0x7fffu + ((u >> 16) & 1u)) >> 16;
    return (unsigned short)r;
}
__device__ __forceinline__ float bf2f(unsigned short x) {
    return __builtin_bit_cast(float, ((unsigned)x) << 16);
}
__device__ __forceinline__ float wred(float v) {
#pragma unroll
    for (int o = 32; o > 0; o >>= 1) v += __shfl_xor(v, o, 64);
    return v;
}

// XOR swizzle for the 128x256-short stage-activation buffer (512 B rows).
// Bank = (byte/4)%32; a 16-B block b = scol>>3 covers bank group (b mod 8).
// XOR the LOW 3 bits of the block index with row&7.
__device__ __forceinline__ int SW(int row, int scol) {
    return row * 256 + (((scol >> 3) ^ (row & 7)) << 3) + (scol & 7);
}
// f32 variant for 16-row x 512-f32 LDS tiles (2048 B rows, 128 16-B blocks).
__device__ __forceinline__ int SW32(int row, int col) {
    return row * 512 + (((col >> 2) ^ (row & 7)) << 2) + (col & 3);
}

// ---------------------------------------------------------------------------
// Merged prep kernel.  Grid 1648 blocks.  UNCHANGED.
// ---------------------------------------------------------------------------
__global__ __launch_bounds__(256) void prep_all(
    const float* __restrict__ enc,
    const float* __restrict__ kW1, const float* __restrict__ kW2, const float* __restrict__ kW3,
    const float* __restrict__ vW1, const float* __restrict__ vW2, const float* __restrict__ vW3,
    const float* __restrict__ dsW, const float* __restrict__ ffW1,
    const float* __restrict__ ffW2, const float* __restrict__ deW1,
    const float* __restrict__ deW2, const float* __restrict__ deW3,
    unsigned short* __restrict__ XF, unsigned short* __restrict__ WP,
    float* __restrict__ W1L, unsigned short* __restrict__ WG) {
    __shared__ float T[32][257];
    int bid = blockIdx.x, tid = threadIdx.x;
    if (bid < 512) {
        int t0 = bid * 32;
        const float* src = enc + (size_t)t0 * 256;
#pragma unroll
        for (int it = 0; it < 8; ++it) {
            int f4 = it * 256 + tid;
            int row = f4 >> 6, c = (f4 & 63) * 4;
            float4 v = *(const float4*)(src + row * 256 + c);
            T[row][c] = v.x; T[row][c + 1] = v.y; T[row][c + 2] = v.z; T[row][c + 3] = v.w;
        }
        __syncthreads();
        int tile = t0 >> 7, g = (t0 >> 6) & 1, nt0 = (t0 >> 4) & 3;
#pragma unroll
        for (int i = 0; i < 32; i += 8) {
            int o = tid * 32 + i;
            int lane = (o >> 3) & 63, ntp = (o >> 9) & 1, kc = o >> 10;
            int id = lane & 15, quad = lane >> 4;
            __align__(16) unsigned short p[8];
#pragma unroll
            for (int j = 0; j < 8; ++j) p[j] = f2bf(T[ntp * 16 + id][kc * 32 + quad * 8 + j]);
            size_t dsto = ((size_t)((((tile * 8 + kc) * 2 + g) * 4 + (nt0 + ntp)) * 64 + lane)) * 8;
            *(uint4*)(XF + dsto) = *(uint4*)p;
        }
    } else if (bid < 1280) {
        int lb = bid - 512;
        int combo = lb / 24, r = lb % 24;
        int st = r >> 3, kc = r & 7;
        int kvv = combo >> 4, l = (combo >> 3) & 1, h = combo & 7;
        unsigned short* dstc = WP + (size_t)combo * 147456;
        if (st < 2) {
            const float* W = (st == 0) ? (kvv ? vW1 : kW1) : (kvv ? vW2 : kW2);
            int rows = (st == 0) ? 257 : 256;
            const float* src = W + ((size_t)(l * 8 + h) * rows + kc * 32) * 256;
#pragma unroll
            for (int it = 0; it < 8; ++it) {
                int f4 = it * 256 + tid;
                int row = f4 >> 6, c = (f4 & 63) * 4;
                float4 v = *(const float4*)(src + (size_t)row * 256 + c);
                T[row][c] = v.x; T[row][c + 1] = v.y; T[row][c + 2] = v.z; T[row][c + 3] = v.w;
            }
            __syncthreads();
            unsigned short* dst = dstc + st * 65536 + kc * 8192;
#pragma unroll
            for (int i = 0; i < 32; i += 8) {
                int o = tid * 32 + i;
                int lane = (o >> 3) & 63, ftile = o >> 9;
                int id = lane & 15, quad = lane >> 4;
                __align__(16) unsigned short p[8];
#pragma unroll
                for (int j = 0; j < 8; ++j) p[j] = f2bf(T[quad * 8 + j][ftile * 16 + id]);
                *(uint4*)(dst + o) = *(uint4*)p;
            }
            if (st == 0 && kc == 0) {
                const float* hw = (kvv ? vW1 : kW1) + (size_t)(l * 8 + h) * 257 * 256;
                W1L[combo * 256 + tid] = hw[65536 + tid];
            }
        } else {
            const float* src = (kvv ? vW3 : kW3) + ((size_t)(l * 8 + h) * 256 + kc * 32) * 64;
#pragma unroll
            for (int it = 0; it < 2; ++it) {
                int f4 = it * 256 + tid;
                int row = f4 >> 4, c = (f4 & 15) * 4;
                float4 v = *(const float4*)(src + (size_t)row * 64 + c);
                T[row][c] = v.x; T[row][c + 1] = v.y; T[row][c + 2] = v.z; T[row][c + 3] = v.w;
            }
            __syncthreads();
            unsigned short* dst = dstc + 131072 + kc * 2048;
            int o = tid * 8;
            int lane = tid & 63, ftile = tid >> 6;
            int id = lane & 15, quad = lane >> 4;
            __align__(16) unsigned short p[8];
#pragma unroll
            for (int j = 0; j < 8; ++j) p[j] = f2bf(T[quad * 8 + j][ftile * 16 + id]);
            *(uint4*)(dst + o) = *(uint4*)p;
        }
    } else {
        int lb0 = bid - 1280;
        const float* src; int N, kc, ng; size_t base;
        if (lb0 < 32)       { int lb = lb0;       src = dsW;           N = 512; base = 0;       kc = lb >> 2; ng = lb & 3; }
        else if (lb0 < 96)  { int lb = lb0 - 32;  src = ffW1;          N = 512; base = 131072;  kc = lb >> 2; ng = lb & 3; }
        else if (lb0 < 160) { int lb = lb0 - 96;  src = ffW1 + 262144; N = 512; base = 393216;  kc = lb >> 2; ng = lb & 3; }
        else if (lb0 < 224) { int lb = lb0 - 160; src = ffW2;          N = 512; base = 655360;  kc = lb >> 2; ng = lb & 3; }
        else if (lb0 < 288) { int lb = lb0 - 224; src = ffW2 + 262144; N = 512; base = 917504;  kc = lb >> 2; ng = lb & 3; }
        else if (lb0 < 320) { int lb = lb0 - 288; src = deW1;          N = 256; base = 1179648; kc = lb >> 1; ng = lb & 1; }
        else if (lb0 < 336) { int lb = lb0 - 320; src = deW2;          N = 256; base = 1310720; kc = lb >> 1; ng = lb & 1; }
        else                { int lb = lb0 - 336; src = deW3;          N = 512; base = 1376256; kc = lb >> 2; ng = lb & 3; }
        int NTl = N >> 4;
        const float* s = src + (size_t)(kc * 32) * N + ng * 128;
#pragma unroll
        for (int it = 0; it < 4; ++it) {
            int f4 = it * 256 + tid;
            int row = f4 >> 5, c = (f4 & 31) * 4;
            float4 v = *(const float4*)(s + (size_t)row * N + c);
            T[row][c] = v.x; T[row][c + 1] = v.y; T[row][c + 2] = v.z; T[row][c + 3] = v.w;
        }
        __syncthreads();
        unsigned short* d = WG + base + (size_t)(kc * NTl + ng * 8) * 512;
#pragma unroll
        for (int i = 0; i < 16; i += 8) {
            int o = tid * 16 + i;
            int lane = (o >> 3) & 63, ntl = o >> 9;
            int id = lane & 15, quad = lane >> 4;
            __align__(16) unsigned short p[8];
#pragma unroll
            for (int j = 0; j < 8; ++j) p[j] = f2bf(T[quad * 8 + j][ntl * 16 + id]);
            *(uint4*)(d + o) = *(uint4*)p;
        }
    }
}

// Continuous cross-stage weight-load step: s in [0,24).
#define LDW(S, DST)                                                                              \
    do {                                                                                         \
        if ((S) < 8) {                                                                           \
            _Pragma("unroll") for (int ft_ = 0; ft_ < 4; ++ft_)                                  \
                (DST)[ft_] = *(const short8*)(WF1 + (size_t)(((S) * 16 + wf * 4 + ft_) * 64 + lane) * 8); \
        } else if ((S) < 16) {                                                                   \
            _Pragma("unroll") for (int ft_ = 0; ft_ < 4; ++ft_)                                  \
                (DST)[ft_] = *(const short8*)(WF2 + (size_t)((((S) - 8) * 16 + wf * 4 + ft_) * 64 + lane) * 8); \
        } else if ((S) < 24) {                                                                   \
            _Pragma("unroll") for (int ft_ = 0; ft_ < 4; ++ft_)                                  \
                (DST)[ft_] = *(const short8*)(WF3 + (size_t)((((S) - 16) * 4 + ft_) * 64 + lane) * 8); \
        }                                                                                        \
    } while (0)

// ---------------------------------------------------------------------------
// Fused per-head MLP (R3/R6-verified structure) + T5 s_setprio around the
// MFMA clusters (2 blocks/CU at different stages -> wave role diversity).
// Everything else UNCHANGED.
// ---------------------------------------------------------------------------
__global__ __launch_bounds__(512, 4) void heads_mlp(
    const float* __restrict__ tu, const unsigned short* __restrict__ XF,
    const unsigned short* __restrict__ WP, const float* __restrict__ W1L,
    const float* __restrict__ kb1, const float* __restrict__ kb2, const float* __restrict__ kb3,
    const float* __restrict__ vb1, const float* __restrict__ vb2, const float* __restrict__ vb3,
    unsigned short* __restrict__ KV) {
    __shared__ __align__(16) unsigned short smem[32768];   // 65536 B

    const int tid = threadIdx.x;
    const int wave = tid >> 6, lane = tid & 63, id = lane & 15, quad = lane >> 4;
    const int wf = wave & 3, wt = wave >> 2;
    const int bx = blockIdx.x;
    const int xcd = bx & 7;
    const int idx = bx >> 3;
    const int combo = xcd * 4 + (idx & 3);
    const int t128 = idx >> 2;
    const int kvv = combo >> 4, l = (combo >> 3) & 1, h = combo & 7;
    const int r0 = t128 * 128;
    const unsigned short* WF1 = WP + (size_t)combo * 147456;
    const unsigned short* WF2 = WF1 + 65536;
    const unsigned short* WF3 = WF1 + 131072;
    const float* b1 = (kvv ? vb1 : kb1) + (l * 8 + h) * 256;
    const float* b2 = (kvv ? vb2 : kb2) + (l * 8 + h) * 256;
    const float* b3 = (kvv ? vb3 : kb3) + (l * 8 + h) * 64;

    short8 afb[2][4];
    LDW(0, afb[0]);
    LDW(1, afb[1]);
    {
        const uint4* s = (const uint4*)(XF + (size_t)t128 * 32768);
        uint4* d = (uint4*)smem;
#pragma unroll
        for (int it = 0; it < 8; ++it) d[it * 512 + tid] = s[it * 512 + tid];
    }
    __syncthreads();

    f32x4 acc[4][4];
#pragma unroll
    for (int i = 0; i < 4; ++i)
#pragma unroll
        for (int j = 0; j < 4; ++j) acc[i][j] = (f32x4){0.f, 0.f, 0.f, 0.f};

    // stage 1 (weight steps 0..7, prefetch 2..9)
#pragma unroll
    for (int kc = 0; kc < 8; ++kc) {
        short8 tn[4];
        LDW(kc + 2, tn);
        short8 bf[4];
#pragma unroll
        for (int nt = 0; nt < 4; ++nt)
            bf[nt] = *(const short8*)(smem + (size_t)(kc * 8 + wt * 4 + nt) * 512 + lane * 8);
        __builtin_amdgcn_s_setprio(1);
#pragma unroll
        for (int ft = 0; ft < 4; ++ft)
#pragma unroll
            for (int nt = 0; nt < 4; ++nt)
                acc[ft][nt] = __builtin_amdgcn_mfma_f32_16x16x32_bf16(afb[kc & 1][ft], bf[nt], acc[ft][nt], 0, 0, 0);
        __builtin_amdgcn_s_setprio(0);
#pragma unroll
        for (int ft = 0; ft < 4; ++ft) afb[kc & 1][ft] = tn[ft];
    }
    __syncthreads();
    {
        float ur[4];
#pragma unroll
        for (int nt = 0; nt < 4; ++nt) ur[nt] = tu[r0 + wt * 64 + nt * 16 + id];
#pragma unroll
        for (int ft = 0; ft < 4; ++ft) {
            int fb = wf * 64 + ft * 16 + quad * 4;
            float4 bb = *(const float4*)(b1 + fb);
            float4 wl = *(const float4*)(W1L + combo * 256 + fb);
            const float* bbp = (const float*)&bb;
            const float* wlp = (const float*)&wl;
#pragma unroll
            for (int nt = 0; nt < 4; ++nt) {
                int row = wt * 64 + nt * 16 + id;
                unsigned short p[4];
#pragma unroll
                for (int r = 0; r < 4; ++r) {
                    float v = acc[ft][nt][r] + bbp[r] + ur[nt] * wlp[r];
                    p[r] = f2bf(fmaxf(v, 0.f));
                }
                uint2 pk;
                pk.x = (unsigned)p[0] | ((unsigned)p[1] << 16);
                pk.y = (unsigned)p[2] | ((unsigned)p[3] << 16);
                *(uint2*)(smem + SW(row, fb)) = pk;
            }
        }
    }
    __syncthreads();

    // stage 2 (weight steps 8..15, prefetch 10..17)
#pragma unroll
    for (int i = 0; i < 4; ++i)
#pragma unroll
        for (int j = 0; j < 4; ++j) acc[i][j] = (f32x4){0.f, 0.f, 0.f, 0.f};
#pragma unroll
    for (int kc = 0; kc < 8; ++kc) {
        short8 tn[4];
        LDW(kc + 10, tn);
        short8 bf[4];
#pragma unroll
        for (int nt = 0; nt < 4; ++nt)
            bf[nt] = *(const short8*)(smem + SW(wt * 64 + nt * 16 + id, kc * 32 + quad * 8));
        __builtin_amdgcn_s_setprio(1);
#pragma unroll
        for (int ft = 0; ft < 4; ++ft)
#pragma unroll
            for (int nt = 0; nt < 4; ++nt)
                acc[ft][nt] = __builtin_amdgcn_mfma_f32_16x16x32_bf16(afb[kc & 1][ft], bf[nt], acc[ft][nt], 0, 0, 0);
        __builtin_amdgcn_s_setprio(0);
#pragma unroll
        for (int ft = 0; ft < 4; ++ft) afb[kc & 1][ft] = tn[ft];
    }
    __syncthreads();
#pragma unroll
    for (int ft = 0; ft < 4; ++ft) {
        int fb = wf * 64 + ft * 16 + quad * 4;
        float4 bb = *(const float4*)(b2 + fb);
        const float* bbp = (const float*)&bb;
#pragma unroll
        for (int nt = 0; nt < 4; ++nt) {
            int row = wt * 64 + nt * 16 + id;
            unsigned short p[4];
#pragma unroll
            for (int r = 0; r < 4; ++r)
                p[r] = f2bf(fmaxf(acc[ft][nt][r] + bbp[r], 0.f));
            uint2 pk;
            pk.x = (unsigned)p[0] | ((unsigned)p[1] << 16);
            pk.y = (unsigned)p[2] | ((unsigned)p[3] << 16);
            *(uint2*)(smem + SW(row, fb)) = pk;
        }
    }
    __syncthreads();

    // stage 3 (weight steps 16..23, prefetch 18..23)
    f32x4 a3[4];
#pragma unroll
    for (int i = 0; i < 4; ++i) a3[i] = (f32x4){0.f, 0.f, 0.f, 0.f};
#pragma unroll
    for (int kc = 0; kc < 8; ++kc) {
        short8 tn[4];
        if (kc + 18 < 24) LDW(kc + 18, tn);
        short8 b3f = *(const short8*)(smem + SW(wave * 16 + id, kc * 32 + quad * 8));
        __builtin_amdgcn_s_setprio(1);
#pragma unroll
        for (int ft = 0; ft < 4; ++ft)
            a3[ft] = __builtin_amdgcn_mfma_f32_16x16x32_bf16(afb[kc & 1][ft], b3f, a3[ft], 0, 0, 0);
        __builtin_amdgcn_s_setprio(0);
        if (kc + 18 < 24) {
#pragma unroll
            for (int ft = 0; ft < 4; ++ft) afb[kc & 1][ft] = tn[ft];
        }
    }
    __syncthreads();
    {
        int tl = wave * 16 + id;
#pragma unroll
        for (int ft = 0; ft < 4; ++ft) {
            int dk0 = ft * 16 + quad * 4;
            float4 bb = *(const float4*)(b3 + dk0);
            const float* bbp = (const float*)&bb;
            unsigned short p[4];
#pragma unroll
            for (int r = 0; r < 4; ++r) p[r] = f2bf(a3[ft][r] + bbp[r]);
            uint2 pk;
            pk.x = (unsigned)p[0] | ((unsigned)p[1] << 16);
            pk.y = (unsigned)p[2] | ((unsigned)p[3] << 16);
            *(uint2*)(smem + (size_t)tl * 72 + dk0) = pk;
        }
    }
    __syncthreads();
    {
#pragma unroll
        for (int it = 0; it < 2; ++it) {
            int tl = it * 64 + (tid >> 3), part = tid & 7;
            uint4 v = *(const uint4*)(smem + (size_t)tl * 72 + part * 8);
            size_t base = ((size_t)combo << 20) + (size_t)(r0 + tl) * 64 + part * 8;
            *(uint4*)(KV + base) = v;
        }
    }
}

// ---------------------------------------------------------------------------
// Tail megakernel: ds-GEMM -> [attn+LN1+FF1+FF2+LN2] x2 -> de1+de2+de3.
// One block per 16 rows.  Grid 64 x 512 thr (1 block/CU -> VGPR headroom).
// R9: attention s-loop fully unrolled (8 KV gather batches in flight);
// de2/de3 kc loops unrolled so weight loads hoist across iterations.
// ---------------------------------------------------------------------------
__global__ __launch_bounds__(512) void tail_fused(
    const float* __restrict__ enc, const int* __restrict__ mid,
    const int* __restrict__ ip,
    const unsigned short* __restrict__ WGds, const float* __restrict__ dsb,
    const unsigned short* __restrict__ KV,
    const int* __restrict__ left, const int* __restrict__ right,
    const float* __restrict__ ln1_g, const float* __restrict__ ln1_b,
    const float* __restrict__ ln2_g, const float* __restrict__ ln2_b,
    const unsigned short* __restrict__ Wff1_0, const unsigned short* __restrict__ Wff1_1,
    const float* __restrict__ ffb1,
    const unsigned short* __restrict__ Wff2_0, const unsigned short* __restrict__ Wff2_1,
    const float* __restrict__ ffb2,
    const unsigned short* __restrict__ Wde1, const float* __restrict__ deb1,
    const unsigned short* __restrict__ Wde2, const float* __restrict__ deb2,
    const unsigned short* __restrict__ Wde3, const float* __restrict__ deb3,
    float* __restrict__ out) {
    __shared__ __align__(16) char SMEM[65536];
    float* AV = (float*)SMEM;                       // [16][512] f32, SW32
    float* XW = (float*)(SMEM + 32768);             // [16][512] f32, SW32
    unsigned short* F1 = (unsigned short*)SMEM;     // [16][520] bf16 (alias AV)
    unsigned short* XD = (unsigned short*)SMEM;     // [16][520] bf16 (alias AV)
    unsigned short* D1 = (unsigned short*)(SMEM + 32768);          // [16][264]
    unsigned short* D2 = (unsigned short*)(SMEM + 32768 + 8448);   // [16][264]

    const int tid = threadIdx.x, wave = tid >> 6, lane = tid & 63;
    const int id = lane & 15, quad = lane >> 4;
    const int m0 = blockIdx.x * 16;
    const int iv = ip[0];

    // ---- Phase 0: ds gemm with fused gather -> AV
    {
        int r0g = m0 + id;
        const float* a0p = enc + (((size_t)((r0g >> 7) * 8 + iv)) * 256 + mid[r0g & 127]) * 256 + quad * 8;
        f32x4 acc[4];
#pragma unroll
        for (int i = 0; i < 4; ++i) acc[i] = (f32x4){0.f, 0.f, 0.f, 0.f};
#pragma unroll
        for (int kc = 0; kc < 8; ++kc) {
            float4 u0 = *(const float4*)(a0p + kc * 32);
            float4 u1 = *(const float4*)(a0p + kc * 32 + 4);
            short8 a0;
            a0[0] = (short)f2bf(u0.x); a0[1] = (short)f2bf(u0.y); a0[2] = (short)f2bf(u0.z); a0[3] = (short)f2bf(u0.w);
            a0[4] = (short)f2bf(u1.x); a0[5] = (short)f2bf(u1.y); a0[6] = (short)f2bf(u1.z); a0[7] = (short)f2bf(u1.w);
#pragma unroll
            for (int nt = 0; nt < 4; ++nt) {
                int ntile = wave * 4 + nt;
                short8 bw = *(const short8*)(WGds + (size_t)((kc * 32 + ntile) * 64 + lane) * 8);
                acc[nt] = __builtin_amdgcn_mfma_f32_16x16x32_bf16(a0, bw, acc[nt], 0, 0, 0);
            }
        }
#pragma unroll
        for (int nt = 0; nt < 4; ++nt) {
            int n0 = (wave * 4 + nt) * 16;
            float bv = dsb[n0 + id];
#pragma unroll
            for (int r = 0; r < 4; ++r)
                AV[SW32(quad * 4 + r, n0 + id)] = acc[nt][r] + bv;
        }
    }
    __syncthreads();

    // ---- Two transformer layers
    for (int l = 0; l < 2; ++l) {
        const float* g1 = ln1_g + l * 512;
        const float* bb1 = ln1_b + l * 512;
        const float* g2 = ln2_g + l * 512;
        const float* bb2 = ln2_b + l * 512;
        const unsigned short* Wf1 = l ? Wff1_1 : Wff1_0;
        const unsigned short* Wf2 = l ? Wff2_1 : Wff2_0;
        const float* fb1 = ffb1 + l * 512;
        const float* fb2 = ffb2 + l * 512;

        // -- Phase 1: attention + residual + LN1 -> XW (wave handles 2 rows)
#pragma unroll
        for (int rr = 0; rr < 2; ++rr) {
            int r = wave * 2 + rr;
            int gid = m0 + r;
            int b = gid >> 7, m = gid & 127;
            int lt = left[m], rt = right[m];
            int h = lane >> 3, d8 = lane & 7;
            const unsigned short* kb = KV + ((size_t)(l * 8 + h) << 20);
            const unsigned short* vb = KV + ((size_t)(16 + l * 8 + h) << 20);
            float av8[8], att8[8];
            {
                float4 u0 = *(const float4*)(&AV[SW32(r, lane * 8)]);
                float4 u1 = *(const float4*)(&AV[SW32(r, lane * 8 + 4)]);
                av8[0] = u0.x; av8[1] = u0.y; av8[2] = u0.z; av8[3] = u0.w;
                av8[4] = u1.x; av8[5] = u1.y; av8[6] = u1.z; av8[7] = u1.w;
            }
#pragma unroll
            for (int j = 0; j < 8; ++j) att8[j] = 0.f;
#pragma unroll
            for (int s = 0; s < 8; ++s) {
                int t1 = (s < iv) ? m : rt;
                size_t o0 = (size_t)((b * 8 + s) * 256 + lt) * 64 + d8 * 8;
                size_t o1 = (size_t)((b * 8 + s) * 256 + t1) * 64 + d8 * 8;
                uint4 k0u = *(const uint4*)(kb + o0);
                uint4 k1u = *(const uint4*)(kb + o1);
                uint4 v0u = *(const uint4*)(vb + o0);
                uint4 v1u = *(const uint4*)(vb + o1);
                const unsigned short* k0 = (const unsigned short*)&k0u;
                const unsigned short* k1 = (const unsigned short*)&k1u;
                const unsigned short* v0 = (const unsigned short*)&v0u;
                const unsigned short* v1 = (const unsigned short*)&v1u;
                float p0 = 0.f, p1 = 0.f;
#pragma unroll
                for (int j = 0; j < 8; ++j) {
                    p0 += av8[j] * bf2f(k0[j]);
                    p1 += av8[j] * bf2f(k1[j]);
                }
#pragma unroll
                for (int o = 1; o < 8; o <<= 1) {
                    p0 += __shfl_xor(p0, o, 64);
                    p1 += __shfl_xor(p1, o, 64);
                }
                p0 *= 0.125f; p1 *= 0.125f;
                float mx = fmaxf(p0, p1);
                float e0 = __expf(p0 - mx), e1 = __expf(p1 - mx);
                float inv = 1.f / (e0 + e1);
                float w0 = e0 * inv, w1 = e1 * inv;
#pragma unroll
                for (int j = 0; j < 8; ++j)
                    att8[j] += w0 * bf2f(v0[j]) + w1 * bf2f(v1[j]);
            }
            float x8[8], sum = 0.f;
#pragma unroll
            for (int j = 0; j < 8; ++j) { x8[j] = av8[j] + att8[j]; sum += x8[j]; }
            float mu = wred(sum) * (1.f / 512.f);
            float s2 = 0.f;
#pragma unroll
            for (int j = 0; j < 8; ++j) { float d = x8[j] - mu; s2 += d * d; }
            float rs = rsqrtf(wred(s2) * (1.f / 512.f) + 1e-5f);
            const float* gp = g1 + lane * 8;
            const float* bp = bb1 + lane * 8;
            __align__(16) float vout[8];
#pragma unroll
            for (int j = 0; j < 8; ++j) vout[j] = (x8[j] - mu) * rs * gp[j] + bp[j];
            *(float4*)(&XW[SW32(r, lane * 8)]) = *(float4*)vout;
            *(float4*)(&XW[SW32(r, lane * 8 + 4)]) = *(float4*)(vout + 4);
        }
        __syncthreads();

        // -- Phase 2: FF1 (A from XW, cvt on the fly) -> F1 bf16 (destroys AV)
        {
            f32x4 acc[4];
#pragma unroll
            for (int i = 0; i < 4; ++i) acc[i] = (f32x4){0.f, 0.f, 0.f, 0.f};
            short8 bw[4];
#pragma unroll
            for (int nt = 0; nt < 4; ++nt)
                bw[nt] = *(const short8*)(Wf1 + (size_t)((wave * 4 + nt) * 64 + lane) * 8);
            for (int kc = 0; kc < 16; ++kc) {
                short8 bwn[4];
                if (kc + 1 < 16) {
#pragma unroll
                    for (int nt = 0; nt < 4; ++nt)
                        bwn[nt] = *(const short8*)(Wf1 + (size_t)(((kc + 1) * 32 + wave * 4 + nt) * 64 + lane) * 8);
                }
                float4 u0 = *(const float4*)(&XW[SW32(id, kc * 32 + quad * 8)]);
                float4 u1 = *(const float4*)(&XW[SW32(id, kc * 32 + quad * 8 + 4)]);
                short8 a0;
                a0[0] = (short)f2bf(u0.x); a0[1] = (short)f2bf(u0.y); a0[2] = (short)f2bf(u0.z); a0[3] = (short)f2bf(u0.w);
                a0[4] = (short)f2bf(u1.x); a0[5] = (short)f2bf(u1.y); a0[6] = (short)f2bf(u1.z); a0[7] = (short)f2bf(u1.w);
#pragma unroll
                for (int nt = 0; nt < 4; ++nt)
                    acc[nt] = __builtin_amdgcn_mfma_f32_16x16x32_bf16(a0, bw[nt], acc[nt], 0, 0, 0);
#pragma unroll
                for (int nt = 0; nt < 4; ++nt) bw[nt] = bwn[nt];
            }
            __syncthreads();   // AV reads (ph1) done block-wide before F1 writes
#pragma unroll
            for (int nt = 0; nt < 4; ++nt) {
                int n0 = (wave * 4 + nt) * 16;
                float bv = fb1[n0 + id];
#pragma unroll
                for (int r = 0; r < 4; ++r)
                    F1[(quad * 4 + r) * 520 + n0 + id] = f2bf(fmaxf(acc[nt][r] + bv, 0.f));
            }
        }
        __syncthreads();

        // -- Phase 3: FF2 (A from F1) + bias + residual into XW in-place
        {
            f32x4 acc[4];
#pragma unroll
            for (int i = 0; i < 4; ++i) acc[i] = (f32x4){0.f, 0.f, 0.f, 0.f};
            short8 bw[4], a0;
#pragma unroll
            for (int nt = 0; nt < 4; ++nt)
                bw[nt] = *(const short8*)(Wf2 + (size_t)((wave * 4 + nt) * 64 + lane) * 8);
            a0 = *(const short8*)(&F1[id * 520 + quad * 8]);
            for (int kc = 0; kc < 16; ++kc) {
                short8 bwn[4], a0n;
                if (kc + 1 < 16) {
#pragma unroll
                    for (int nt = 0; nt < 4; ++nt)
                        bwn[nt] = *(const short8*)(Wf2 + (size_t)(((kc + 1) * 32 + wave * 4 + nt) * 64 + lane) * 8);
                    a0n = *(const short8*)(&F1[id * 520 + (kc + 1) * 32 + quad * 8]);
                }
#pragma unroll
                for (int nt = 0; nt < 4; ++nt)
                    acc[nt] = __builtin_amdgcn_mfma_f32_16x16x32_bf16(a0, bw[nt], acc[nt], 0, 0, 0);
#pragma unroll
                for (int nt = 0; nt < 4; ++nt) bw[nt] = bwn[nt];
                a0 = a0n;
            }
#pragma unroll
            for (int nt = 0; nt < 4; ++nt) {
                int n0 = (wave * 4 + nt) * 16;
                float bv = fb2[n0 + id];
#pragma unroll
                for (int r = 0; r < 4; ++r)
                    XW[SW32(quad * 4 + r, n0 + id)] += acc[nt][r] + bv;   // x + ff
            }
        }
        __syncthreads();

        // -- Phase 4: LN2; l==0 -> AV (f32, next layer); l==1 -> XD (bf16)
#pragma unroll
        for (int rr = 0; rr < 2; ++rr) {
            int r = wave * 2 + rr;
            float x8[8];
            {
                float4 u0 = *(const float4*)(&XW[SW32(r, lane * 8)]);
                float4 u1 = *(const float4*)(&XW[SW32(r, lane * 8 + 4)]);
                x8[0] = u0.x; x8[1] = u0.y; x8[2] = u0.z; x8[3] = u0.w;
                x8[4] = u1.x; x8[5] = u1.y; x8[6] = u1.z; x8[7] = u1.w;
            }
            float sum = 0.f;
#pragma unroll
            for (int j = 0; j < 8; ++j) sum += x8[j];
            float mu = wred(sum) * (1.f / 512.f);
            float s2 = 0.f;
#pragma unroll
            for (int j = 0; j < 8; ++j) { float d = x8[j] - mu; s2 += d * d; }
            float rs = rsqrtf(wred(s2) * (1.f / 512.f) + 1e-5f);
            const float* gp = g2 + lane * 8;
            const float* bp = bb2 + lane * 8;
            __align__(16) float vout[8];
#pragma unroll
            for (int j = 0; j < 8; ++j) vout[j] = (x8[j] - mu) * rs * gp[j] + bp[j];
            if (l == 0) {
                *(float4*)(&AV[SW32(r, lane * 8)]) = *(float4*)vout;
                *(float4*)(&AV[SW32(r, lane * 8 + 4)]) = *(float4*)(vout + 4);
            } else {
                __align__(16) unsigned short pb[8];
#pragma unroll
                for (int j = 0; j < 8; ++j) pb[j] = f2bf(vout[j]);
                *(uint4*)(&XD[r * 520 + lane * 8]) = *(uint4*)pb;
            }
        }
        __syncthreads();
    }

    // ---- Decoder: de1(relu) -> de2(relu) -> de3
    {
        f32x4 acc[2];
        acc[0] = (f32x4){0.f, 0.f, 0.f, 0.f};
        acc[1] = (f32x4){0.f, 0.f, 0.f, 0.f};
        short8 bw[2], a0;
#pragma unroll
        for (int nt = 0; nt < 2; ++nt)
            bw[nt] = *(const short8*)(Wde1 + (size_t)((wave * 2 + nt) * 64 + lane) * 8);
        a0 = *(const short8*)(&XD[id * 520 + quad * 8]);
        for (int kc = 0; kc < 16; ++kc) {
            short8 bwn[2], a0n;
            if (kc + 1 < 16) {
#pragma unroll
                for (int nt = 0; nt < 2; ++nt)
                    bwn[nt] = *(const short8*)(Wde1 + (size_t)(((kc + 1) * 16 + wave * 2 + nt) * 64 + lane) * 8);
                a0n = *(const short8*)(&XD[id * 520 + (kc + 1) * 32 + quad * 8]);
            }
#pragma unroll
            for (int nt = 0; nt < 2; ++nt)
                acc[nt] = __builtin_amdgcn_mfma_f32_16x16x32_bf16(a0, bw[nt], acc[nt], 0, 0, 0);
#pragma unroll
            for (int nt = 0; nt < 2; ++nt) bw[nt] = bwn[nt];
            a0 = a0n;
        }
        __syncthreads();   // XD fully read before D1 (XW region) writes
#pragma unroll
        for (int nt = 0; nt < 2; ++nt) {
            int n0 = (wave * 2 + nt) * 16;
            float bv = deb1[n0 + id];
#pragma unroll
            for (int r = 0; r < 4; ++r)
                D1[(quad * 4 + r) * 264 + n0 + id] = f2bf(fmaxf(acc[nt][r] + bv, 0.f));
        }
    }
    __syncthreads();
    {
        f32x4 acc[2];
        acc[0] = (f32x4){0.f, 0.f, 0.f, 0.f};
        acc[1] = (f32x4){0.f, 0.f, 0.f, 0.f};
#pragma unroll
        for (int kc = 0; kc < 8; ++kc) {
            short8 a0 = *(const short8*)(&D1[id * 264 + kc * 32 + quad * 8]);
#pragma unroll
            for (int nt = 0; nt < 2; ++nt) {
                short8 bw = *(const short8*)(Wde2 + (size_t)((kc * 16 + wave * 2 + nt) * 64 + lane) * 8);
                acc[nt] = __builtin_amdgcn_mfma_f32_16x16x32_bf16(a0, bw, acc[nt], 0, 0, 0);
            }
        }
#pragma unroll
        for (int nt = 0; nt < 2; ++nt) {
            int n0 = (wave * 2 + nt) * 16;
            float bv = deb2[n0 + id];
#pragma unroll
            for (int r = 0; r < 4; ++r)
                D2[(quad * 4 + r) * 264 + n0 + id] = f2bf(fmaxf(acc[nt][r] + bv, 0.f));
        }
    }
    __syncthreads();
    {
        f32x4 acc[4];
#pragma unroll
        for (int i = 0; i < 4; ++i) acc[i] = (f32x4){0.f, 0.f, 0.f, 0.f};
#pragma unroll
        for (int kc = 0; kc < 8; ++kc) {
            short8 a0 = *(const short8*)(&D2[id * 264 + kc * 32 + quad * 8]);
#pragma unroll
            for (int nt = 0; nt < 4; ++nt) {
                short8 bw = *(const short8*)(Wde3 + (size_t)((kc * 32 + wave * 4 + nt) * 64 + lane) * 8);
                acc[nt] = __builtin_amdgcn_mfma_f32_16x16x32_bf16(a0, bw, acc[nt], 0, 0, 0);
            }
        }
#pragma unroll
        for (int nt = 0; nt < 4; ++nt) {
            int n0 = (wave * 4 + nt) * 16;
            float bv = deb3[n0 + id];
#pragma unroll
            for (int r = 0; r < 4; ++r)
                out[(size_t)(m0 + quad * 4 + r) * 512 + n0 + id] = acc[nt][r] + bv;
        }
    }
}

// ---------------------------------------------------------------------------
extern "C" void kernel_launch(void* const* d_in, const int* in_sizes, int n_in,
                              void* d_out, int out_size, void* d_ws, size_t ws_size,
                              hipStream_t stream) {
    const float* encoded = (const float*)d_in[0];
    const float* true_u  = (const float*)d_in[1];
    const int* mid_idx   = (const int*)d_in[2];
    const int* left_idx  = (const int*)d_in[3];
    const int* right_idx = (const int*)d_in[4];
    const int* ip        = (const int*)d_in[5];
    const float* ds_W = (const float*)d_in[6];
    const float* ds_b = (const float*)d_in[7];
    const float* kW1 = (const float*)d_in[8];
    const float* kb1 = (const float*)d_in[9];
    const float* kW2 = (const float*)d_in[10];
    const float* kb2 = (const float*)d_in[11];
    const float* kW3 = (const float*)d_in[12];
    const float* kb3 = (const float*)d_in[13];
    const float* vW1 = (const float*)d_in[14];
    const float* vb1 = (const float*)d_in[15];
    const float* vW2 = (const float*)d_in[16];
    const float* vb2 = (const float*)d_in[17];
    const float* vW3 = (const float*)d_in[18];
    const float* vb3 = (const float*)d_in[19];
    const float* ln1_g = (const float*)d_in[20];
    const float* ln1_b = (const float*)d_in[21];
    const float* ln2_g = (const float*)d_in[22];
    const float* ln2_b = (const float*)d_in[23];
    const float* ffW1 = (const float*)d_in[24];
    const float* ffb1 = (const float*)d_in[25];
    const float* ffW2 = (const float*)d_in[26];
    const float* ffb2 = (const float*)d_in[27];
    const float* deW1 = (const float*)d_in[28];
    const float* deb1 = (const float*)d_in[29];
    const float* deW2 = (const float*)d_in[30];
    const float* deb2 = (const float*)d_in[31];
    const float* deW3 = (const float*)d_in[32];
    const float* deb3 = (const float*)d_in[33];

    char* ws = (char*)d_ws;
    unsigned short* XF    = (unsigned short*)(ws + 0);          //  8,388,608
    unsigned short* WP    = (unsigned short*)(ws + 8388608);    //  9,437,184
    float* W1L            = (float*)(ws + 17825792);            //     32,768
    unsigned short* KV    = (unsigned short*)(ws + 17858560);   // 67,108,864
    unsigned short* WG    = (unsigned short*)(ws + 84967424);   //  3,014,656

    // WG image offsets (halves)
    unsigned short* WGds    = WG + 0;
    unsigned short* WGff1_0 = WG + 131072;
    unsigned short* WGff1_1 = WG + 393216;
    unsigned short* WGff2_0 = WG + 655360;
    unsigned short* WGff2_1 = WG + 917504;
    unsigned short* WGde1   = WG + 1179648;
    unsigned short* WGde2   = WG + 1310720;
    unsigned short* WGde3   = WG + 1376256;

    prep_all<<<1648, 256, 0, stream>>>(encoded, kW1, kW2, kW3, vW1, vW2, vW3,
                                       ds_W, ffW1, ffW2, deW1, deW2, deW3,
                                       XF, WP, W1L, WG);
    heads_mlp<<<4096, 512, 0, stream>>>(true_u, XF, WP, W1L, kb1, kb2, kb3,
                                        vb1, vb2, vb3, KV);
    tail_fused<<<64, 512, 0, stream>>>(encoded, mid_idx, ip, WGds, ds_b, KV,
                                       left_idx, right_idx,
                                       ln1_g, ln1_b, ln2_g, ln2_b,
                                       WGff1_0, WGff1_1, ffb1,
                                       WGff2_0, WGff2_1, ffb2,
                                       WGde1, deb1, WGde2, deb2, WGde3, deb3,
                                       (float*)d_out);
}

// Round 10
// 368.130 us; speedup vs baseline: 1.9731x; 1.9731x over previous
//
#include <hip/hip_runtime.h>
#include <hip/hip_bf16.h>

// Problem constants
#define NB 8
#define NS 8
#define NT 256
#define ND 256
#define NH 8
#define NDK 64
#define NHD 512
#define NL 2
#define NF 256
#define NR 512
#define NM 128
#define NTOK 16384   // B*S*T
#define NROW 1024    // B*M

typedef __attribute__((ext_vector_type(8))) short short8;
typedef __attribute__((ext_vector_type(4))) float f32x4;

// NOTE (R4+R9 post-mortems): heads_mlp sits at exactly 128 unified regs/wave
// (launch_bounds 512,4).  ANY scheduling-opaque instruction in its K-loops
// (inline-asm cvt_pk, s_setprio, sched_barrier) fences the scheduler, extends
// prefetch live ranges past 128 regs -> scratch spill (WRITE 72MB -> 1.2GB+,
// 193 -> 535+ us).  Keep the K-loops pure compiler-scheduled HIP.
__device__ __forceinline__ unsigned short f2bf(float x) {
    unsigned u = __builtin_bit_cast(unsigned, x);
    unsigned r = (u + 0x7fffu + ((u >> 16) & 1u)) >> 16;
    return (unsigned short)r;
}
__device__ __forceinline__ float bf2f(unsigned short x) {
    return __builtin_bit_cast(float, ((unsigned)x) << 16);
}
__device__ __forceinline__ float wred(float v) {
#pragma unroll
    for (int o = 32; o > 0; o >>= 1) v += __shfl_xor(v, o, 64);
    return v;
}

// XOR swizzle for the 128x256-short stage-activation buffer (512 B rows).
// Bank = (byte/4)%32; a 16-B block b = scol>>3 covers bank group (b mod 8).
// XOR the LOW 3 bits of the block index with row&7.
__device__ __forceinline__ int SW(int row, int scol) {
    return row * 256 + (((scol >> 3) ^ (row & 7)) << 3) + (scol & 7);
}
// f32 variant for 16-row x 512-f32 LDS tiles (2048 B rows, 128 16-B blocks).
__device__ __forceinline__ int SW32(int row, int col) {
    return row * 512 + (((col >> 2) ^ (row & 7)) << 2) + (col & 3);
}

// ---------------------------------------------------------------------------
// Merged prep kernel.  Grid 1648 blocks.
// ---------------------------------------------------------------------------
__global__ __launch_bounds__(256) void prep_all(
    const float* __restrict__ enc,
    const float* __restrict__ kW1, const float* __restrict__ kW2, const float* __restrict__ kW3,
    const float* __restrict__ vW1, const float* __restrict__ vW2, const float* __restrict__ vW3,
    const float* __restrict__ dsW, const float* __restrict__ ffW1,
    const float* __restrict__ ffW2, const float* __restrict__ deW1,
    const float* __restrict__ deW2, const float* __restrict__ deW3,
    unsigned short* __restrict__ XF, unsigned short* __restrict__ WP,
    float* __restrict__ W1L, unsigned short* __restrict__ WG) {
    __shared__ float T[32][257];
    int bid = blockIdx.x, tid = threadIdx.x;
    if (bid < 512) {
        int t0 = bid * 32;
        const float* src = enc + (size_t)t0 * 256;
#pragma unroll
        for (int it = 0; it < 8; ++it) {
            int f4 = it * 256 + tid;
            int row = f4 >> 6, c = (f4 & 63) * 4;
            float4 v = *(const float4*)(src + row * 256 + c);
            T[row][c] = v.x; T[row][c + 1] = v.y; T[row][c + 2] = v.z; T[row][c + 3] = v.w;
        }
        __syncthreads();
        int tile = t0 >> 7, g = (t0 >> 6) & 1, nt0 = (t0 >> 4) & 3;
#pragma unroll
        for (int i = 0; i < 32; i += 8) {
            int o = tid * 32 + i;
            int lane = (o >> 3) & 63, ntp = (o >> 9) & 1, kc = o >> 10;
            int id = lane & 15, quad = lane >> 4;
            __align__(16) unsigned short p[8];
#pragma unroll
            for (int j = 0; j < 8; ++j) p[j] = f2bf(T[ntp * 16 + id][kc * 32 + quad * 8 + j]);
            size_t dsto = ((size_t)((((tile * 8 + kc) * 2 + g) * 4 + (nt0 + ntp)) * 64 + lane)) * 8;
            *(uint4*)(XF + dsto) = *(uint4*)p;
        }
    } else if (bid < 1280) {
        int lb = bid - 512;
        int combo = lb / 24, r = lb % 24;
        int st = r >> 3, kc = r & 7;
        int kvv = combo >> 4, l = (combo >> 3) & 1, h = combo & 7;
        unsigned short* dstc = WP + (size_t)combo * 147456;
        if (st < 2) {
            const float* W = (st == 0) ? (kvv ? vW1 : kW1) : (kvv ? vW2 : kW2);
            int rows = (st == 0) ? 257 : 256;
            const float* src = W + ((size_t)(l * 8 + h) * rows + kc * 32) * 256;
#pragma unroll
            for (int it = 0; it < 8; ++it) {
                int f4 = it * 256 + tid;
                int row = f4 >> 6, c = (f4 & 63) * 4;
                float4 v = *(const float4*)(src + (size_t)row * 256 + c);
                T[row][c] = v.x; T[row][c + 1] = v.y; T[row][c + 2] = v.z; T[row][c + 3] = v.w;
            }
            __syncthreads();
            unsigned short* dst = dstc + st * 65536 + kc * 8192;
#pragma unroll
            for (int i = 0; i < 32; i += 8) {
                int o = tid * 32 + i;
                int lane = (o >> 3) & 63, ftile = o >> 9;
                int id = lane & 15, quad = lane >> 4;
                __align__(16) unsigned short p[8];
#pragma unroll
                for (int j = 0; j < 8; ++j) p[j] = f2bf(T[quad * 8 + j][ftile * 16 + id]);
                *(uint4*)(dst + o) = *(uint4*)p;
            }
            if (st == 0 && kc == 0) {
                const float* hw = (kvv ? vW1 : kW1) + (size_t)(l * 8 + h) * 257 * 256;
                W1L[combo * 256 + tid] = hw[65536 + tid];
            }
        } else {
            const float* src = (kvv ? vW3 : kW3) + ((size_t)(l * 8 + h) * 256 + kc * 32) * 64;
#pragma unroll
            for (int it = 0; it < 2; ++it) {
                int f4 = it * 256 + tid;
                int row = f4 >> 4, c = (f4 & 15) * 4;
                float4 v = *(const float4*)(src + (size_t)row * 64 + c);
                T[row][c] = v.x; T[row][c + 1] = v.y; T[row][c + 2] = v.z; T[row][c + 3] = v.w;
            }
            __syncthreads();
            unsigned short* dst = dstc + 131072 + kc * 2048;
            int o = tid * 8;
            int lane = tid & 63, ftile = tid >> 6;
            int id = lane & 15, quad = lane >> 4;
            __align__(16) unsigned short p[8];
#pragma unroll
            for (int j = 0; j < 8; ++j) p[j] = f2bf(T[quad * 8 + j][ftile * 16 + id]);
            *(uint4*)(dst + o) = *(uint4*)p;
        }
    } else {
        int lb0 = bid - 1280;
        const float* src; int N, kc, ng; size_t base;
        if (lb0 < 32)       { int lb = lb0;       src = dsW;           N = 512; base = 0;       kc = lb >> 2; ng = lb & 3; }
        else if (lb0 < 96)  { int lb = lb0 - 32;  src = ffW1;          N = 512; base = 131072;  kc = lb >> 2; ng = lb & 3; }
        else if (lb0 < 160) { int lb = lb0 - 96;  src = ffW1 + 262144; N = 512; base = 393216;  kc = lb >> 2; ng = lb & 3; }
        else if (lb0 < 224) { int lb = lb0 - 160; src = ffW2;          N = 512; base = 655360;  kc = lb >> 2; ng = lb & 3; }
        else if (lb0 < 288) { int lb = lb0 - 224; src = ffW2 + 262144; N = 512; base = 917504;  kc = lb >> 2; ng = lb & 3; }
        else if (lb0 < 320) { int lb = lb0 - 288; src = deW1;          N = 256; base = 1179648; kc = lb >> 1; ng = lb & 1; }
        else if (lb0 < 336) { int lb = lb0 - 320; src = deW2;          N = 256; base = 1310720; kc = lb >> 1; ng = lb & 1; }
        else                { int lb = lb0 - 336; src = deW3;          N = 512; base = 1376256; kc = lb >> 2; ng = lb & 3; }
        int NTl = N >> 4;
        const float* s = src + (size_t)(kc * 32) * N + ng * 128;
#pragma unroll
        for (int it = 0; it < 4; ++it) {
            int f4 = it * 256 + tid;
            int row = f4 >> 5, c = (f4 & 31) * 4;
            float4 v = *(const float4*)(s + (size_t)row * N + c);
            T[row][c] = v.x; T[row][c + 1] = v.y; T[row][c + 2] = v.z; T[row][c + 3] = v.w;
        }
        __syncthreads();
        unsigned short* d = WG + base + (size_t)(kc * NTl + ng * 8) * 512;
#pragma unroll
        for (int i = 0; i < 16; i += 8) {
            int o = tid * 16 + i;
            int lane = (o >> 3) & 63, ntl = o >> 9;
            int id = lane & 15, quad = lane >> 4;
            __align__(16) unsigned short p[8];
#pragma unroll
            for (int j = 0; j < 8; ++j) p[j] = f2bf(T[quad * 8 + j][ntl * 16 + id]);
            *(uint4*)(d + o) = *(uint4*)p;
        }
    }
}

// Continuous cross-stage weight-load step: s in [0,24).
#define LDW(S, DST)                                                                              \
    do {                                                                                         \
        if ((S) < 8) {                                                                           \
            _Pragma("unroll") for (int ft_ = 0; ft_ < 4; ++ft_)                                  \
                (DST)[ft_] = *(const short8*)(WF1 + (size_t)(((S) * 16 + wf * 4 + ft_) * 64 + lane) * 8); \
        } else if ((S) < 16) {                                                                   \
            _Pragma("unroll") for (int ft_ = 0; ft_ < 4; ++ft_)                                  \
                (DST)[ft_] = *(const short8*)(WF2 + (size_t)((((S) - 8) * 16 + wf * 4 + ft_) * 64 + lane) * 8); \
        } else if ((S) < 24) {                                                                   \
            _Pragma("unroll") for (int ft_ = 0; ft_ < 4; ++ft_)                                  \
                (DST)[ft_] = *(const short8*)(WF3 + (size_t)((((S) - 16) * 4 + ft_) * 64 + lane) * 8); \
        }                                                                                        \
    } while (0)

// ---------------------------------------------------------------------------
// Fused per-head MLP (R3/R6/R8-verified).  UNCHANGED — no setprio, no asm.
// ---------------------------------------------------------------------------
__global__ __launch_bounds__(512, 4) void heads_mlp(
    const float* __restrict__ tu, const unsigned short* __restrict__ XF,
    const unsigned short* __restrict__ WP, const float* __restrict__ W1L,
    const float* __restrict__ kb1, const float* __restrict__ kb2, const float* __restrict__ kb3,
    const float* __restrict__ vb1, const float* __restrict__ vb2, const float* __restrict__ vb3,
    unsigned short* __restrict__ KV) {
    __shared__ __align__(16) unsigned short smem[32768];   // 65536 B

    const int tid = threadIdx.x;
    const int wave = tid >> 6, lane = tid & 63, id = lane & 15, quad = lane >> 4;
    const int wf = wave & 3, wt = wave >> 2;
    const int bx = blockIdx.x;
    const int xcd = bx & 7;
    const int idx = bx >> 3;
    const int combo = xcd * 4 + (idx & 3);
    const int t128 = idx >> 2;
    const int kvv = combo >> 4, l = (combo >> 3) & 1, h = combo & 7;
    const int r0 = t128 * 128;
    const unsigned short* WF1 = WP + (size_t)combo * 147456;
    const unsigned short* WF2 = WF1 + 65536;
    const unsigned short* WF3 = WF1 + 131072;
    const float* b1 = (kvv ? vb1 : kb1) + (l * 8 + h) * 256;
    const float* b2 = (kvv ? vb2 : kb2) + (l * 8 + h) * 256;
    const float* b3 = (kvv ? vb3 : kb3) + (l * 8 + h) * 64;

    short8 afb[2][4];
    LDW(0, afb[0]);
    LDW(1, afb[1]);
    {
        const uint4* s = (const uint4*)(XF + (size_t)t128 * 32768);
        uint4* d = (uint4*)smem;
#pragma unroll
        for (int it = 0; it < 8; ++it) d[it * 512 + tid] = s[it * 512 + tid];
    }
    __syncthreads();

    f32x4 acc[4][4];
#pragma unroll
    for (int i = 0; i < 4; ++i)
#pragma unroll
        for (int j = 0; j < 4; ++j) acc[i][j] = (f32x4){0.f, 0.f, 0.f, 0.f};

    // stage 1 (weight steps 0..7, prefetch 2..9)
#pragma unroll
    for (int kc = 0; kc < 8; ++kc) {
        short8 tn[4];
        LDW(kc + 2, tn);
        short8 bf[4];
#pragma unroll
        for (int nt = 0; nt < 4; ++nt)
            bf[nt] = *(const short8*)(smem + (size_t)(kc * 8 + wt * 4 + nt) * 512 + lane * 8);
#pragma unroll
        for (int ft = 0; ft < 4; ++ft)
#pragma unroll
            for (int nt = 0; nt < 4; ++nt)
                acc[ft][nt] = __builtin_amdgcn_mfma_f32_16x16x32_bf16(afb[kc & 1][ft], bf[nt], acc[ft][nt], 0, 0, 0);
#pragma unroll
        for (int ft = 0; ft < 4; ++ft) afb[kc & 1][ft] = tn[ft];
    }
    __syncthreads();
    {
        float ur[4];
#pragma unroll
        for (int nt = 0; nt < 4; ++nt) ur[nt] = tu[r0 + wt * 64 + nt * 16 + id];
#pragma unroll
        for (int ft = 0; ft < 4; ++ft) {
            int fb = wf * 64 + ft * 16 + quad * 4;
            float4 bb = *(const float4*)(b1 + fb);
            float4 wl = *(const float4*)(W1L + combo * 256 + fb);
            const float* bbp = (const float*)&bb;
            const float* wlp = (const float*)&wl;
#pragma unroll
            for (int nt = 0; nt < 4; ++nt) {
                int row = wt * 64 + nt * 16 + id;
                unsigned short p[4];
#pragma unroll
                for (int r = 0; r < 4; ++r) {
                    float v = acc[ft][nt][r] + bbp[r] + ur[nt] * wlp[r];
                    p[r] = f2bf(fmaxf(v, 0.f));
                }
                uint2 pk;
                pk.x = (unsigned)p[0] | ((unsigned)p[1] << 16);
                pk.y = (unsigned)p[2] | ((unsigned)p[3] << 16);
                *(uint2*)(smem + SW(row, fb)) = pk;
            }
        }
    }
    __syncthreads();

    // stage 2 (weight steps 8..15, prefetch 10..17)
#pragma unroll
    for (int i = 0; i < 4; ++i)
#pragma unroll
        for (int j = 0; j < 4; ++j) acc[i][j] = (f32x4){0.f, 0.f, 0.f, 0.f};
#pragma unroll
    for (int kc = 0; kc < 8; ++kc) {
        short8 tn[4];
        LDW(kc + 10, tn);
        short8 bf[4];
#pragma unroll
        for (int nt = 0; nt < 4; ++nt)
            bf[nt] = *(const short8*)(smem + SW(wt * 64 + nt * 16 + id, kc * 32 + quad * 8));
#pragma unroll
        for (int ft = 0; ft < 4; ++ft)
#pragma unroll
            for (int nt = 0; nt < 4; ++nt)
                acc[ft][nt] = __builtin_amdgcn_mfma_f32_16x16x32_bf16(afb[kc & 1][ft], bf[nt], acc[ft][nt], 0, 0, 0);
#pragma unroll
        for (int ft = 0; ft < 4; ++ft) afb[kc & 1][ft] = tn[ft];
    }
    __syncthreads();
#pragma unroll
    for (int ft = 0; ft < 4; ++ft) {
        int fb = wf * 64 + ft * 16 + quad * 4;
        float4 bb = *(const float4*)(b2 + fb);
        const float* bbp = (const float*)&bb;
#pragma unroll
        for (int nt = 0; nt < 4; ++nt) {
            int row = wt * 64 + nt * 16 + id;
            unsigned short p[4];
#pragma unroll
            for (int r = 0; r < 4; ++r)
                p[r] = f2bf(fmaxf(acc[ft][nt][r] + bbp[r], 0.f));
            uint2 pk;
            pk.x = (unsigned)p[0] | ((unsigned)p[1] << 16);
            pk.y = (unsigned)p[2] | ((unsigned)p[3] << 16);
            *(uint2*)(smem + SW(row, fb)) = pk;
        }
    }
    __syncthreads();

    // stage 3 (weight steps 16..23, prefetch 18..23)
    f32x4 a3[4];
#pragma unroll
    for (int i = 0; i < 4; ++i) a3[i] = (f32x4){0.f, 0.f, 0.f, 0.f};
#pragma unroll
    for (int kc = 0; kc < 8; ++kc) {
        short8 tn[4];
        if (kc + 18 < 24) LDW(kc + 18, tn);
        short8 b3f = *(const short8*)(smem + SW(wave * 16 + id, kc * 32 + quad * 8));
#pragma unroll
        for (int ft = 0; ft < 4; ++ft)
            a3[ft] = __builtin_amdgcn_mfma_f32_16x16x32_bf16(afb[kc & 1][ft], b3f, a3[ft], 0, 0, 0);
        if (kc + 18 < 24) {
#pragma unroll
            for (int ft = 0; ft < 4; ++ft) afb[kc & 1][ft] = tn[ft];
        }
    }
    __syncthreads();
    {
        int tl = wave * 16 + id;
#pragma unroll
        for (int ft = 0; ft < 4; ++ft) {
            int dk0 = ft * 16 + quad * 4;
            float4 bb = *(const float4*)(b3 + dk0);
            const float* bbp = (const float*)&bb;
            unsigned short p[4];
#pragma unroll
            for (int r = 0; r < 4; ++r) p[r] = f2bf(a3[ft][r] + bbp[r]);
            uint2 pk;
            pk.x = (unsigned)p[0] | ((unsigned)p[1] << 16);
            pk.y = (unsigned)p[2] | ((unsigned)p[3] << 16);
            *(uint2*)(smem + (size_t)tl * 72 + dk0) = pk;
        }
    }
    __syncthreads();
    {
#pragma unroll
        for (int it = 0; it < 2; ++it) {
            int tl = it * 64 + (tid >> 3), part = tid & 7;
            uint4 v = *(const uint4*)(smem + (size_t)tl * 72 + part * 8);
            size_t base = ((size_t)combo << 20) + (size_t)(r0 + tl) * 64 + part * 8;
            *(uint4*)(KV + base) = v;
        }
    }
}

// ---------------------------------------------------------------------------
// Tail megakernel: ds-GEMM -> [attn+LN1+FF1+FF2+LN2] x2 -> de1+de2+de3.
// One block per 16 rows.  Grid 64 x 512 thr.  R8-verified version
// (attn s-loop at unroll 2 — full unroll risks spill at this VGPR budget).
// ---------------------------------------------------------------------------
__global__ __launch_bounds__(512) void tail_fused(
    const float* __restrict__ enc, const int* __restrict__ mid,
    const int* __restrict__ ip,
    const unsigned short* __restrict__ WGds, const float* __restrict__ dsb,
    const unsigned short* __restrict__ KV,
    const int* __restrict__ left, const int* __restrict__ right,
    const float* __restrict__ ln1_g, const float* __restrict__ ln1_b,
    const float* __restrict__ ln2_g, const float* __restrict__ ln2_b,
    const unsigned short* __restrict__ Wff1_0, const unsigned short* __restrict__ Wff1_1,
    const float* __restrict__ ffb1,
    const unsigned short* __restrict__ Wff2_0, const unsigned short* __restrict__ Wff2_1,
    const float* __restrict__ ffb2,
    const unsigned short* __restrict__ Wde1, const float* __restrict__ deb1,
    const unsigned short* __restrict__ Wde2, const float* __restrict__ deb2,
    const unsigned short* __restrict__ Wde3, const float* __restrict__ deb3,
    float* __restrict__ out) {
    __shared__ __align__(16) char SMEM[65536];
    float* AV = (float*)SMEM;                       // [16][512] f32, SW32
    float* XW = (float*)(SMEM + 32768);             // [16][512] f32, SW32
    unsigned short* F1 = (unsigned short*)SMEM;     // [16][520] bf16 (alias AV)
    unsigned short* XD = (unsigned short*)SMEM;     // [16][520] bf16 (alias AV)
    unsigned short* D1 = (unsigned short*)(SMEM + 32768);          // [16][264]
    unsigned short* D2 = (unsigned short*)(SMEM + 32768 + 8448);   // [16][264]

    const int tid = threadIdx.x, wave = tid >> 6, lane = tid & 63;
    const int id = lane & 15, quad = lane >> 4;
    const int m0 = blockIdx.x * 16;
    const int iv = ip[0];

    // ---- Phase 0: ds gemm with fused gather -> AV
    {
        int r0g = m0 + id;
        const float* a0p = enc + (((size_t)((r0g >> 7) * 8 + iv)) * 256 + mid[r0g & 127]) * 256 + quad * 8;
        f32x4 acc[4];
#pragma unroll
        for (int i = 0; i < 4; ++i) acc[i] = (f32x4){0.f, 0.f, 0.f, 0.f};
#pragma unroll
        for (int kc = 0; kc < 8; ++kc) {
            float4 u0 = *(const float4*)(a0p + kc * 32);
            float4 u1 = *(const float4*)(a0p + kc * 32 + 4);
            short8 a0;
            a0[0] = (short)f2bf(u0.x); a0[1] = (short)f2bf(u0.y); a0[2] = (short)f2bf(u0.z); a0[3] = (short)f2bf(u0.w);
            a0[4] = (short)f2bf(u1.x); a0[5] = (short)f2bf(u1.y); a0[6] = (short)f2bf(u1.z); a0[7] = (short)f2bf(u1.w);
#pragma unroll
            for (int nt = 0; nt < 4; ++nt) {
                int ntile = wave * 4 + nt;
                short8 bw = *(const short8*)(WGds + (size_t)((kc * 32 + ntile) * 64 + lane) * 8);
                acc[nt] = __builtin_amdgcn_mfma_f32_16x16x32_bf16(a0, bw, acc[nt], 0, 0, 0);
            }
        }
#pragma unroll
        for (int nt = 0; nt < 4; ++nt) {
            int n0 = (wave * 4 + nt) * 16;
            float bv = dsb[n0 + id];
#pragma unroll
            for (int r = 0; r < 4; ++r)
                AV[SW32(quad * 4 + r, n0 + id)] = acc[nt][r] + bv;
        }
    }
    __syncthreads();

    // ---- Two transformer layers
    for (int l = 0; l < 2; ++l) {
        const float* g1 = ln1_g + l * 512;
        const float* bb1 = ln1_b + l * 512;
        const float* g2 = ln2_g + l * 512;
        const float* bb2 = ln2_b + l * 512;
        const unsigned short* Wf1 = l ? Wff1_1 : Wff1_0;
        const unsigned short* Wf2 = l ? Wff2_1 : Wff2_0;
        const float* fb1 = ffb1 + l * 512;
        const float* fb2 = ffb2 + l * 512;

        // -- Phase 1: attention + residual + LN1 -> XW (wave handles 2 rows)
#pragma unroll
        for (int rr = 0; rr < 2; ++rr) {
            int r = wave * 2 + rr;
            int gid = m0 + r;
            int b = gid >> 7, m = gid & 127;
            int lt = left[m], rt = right[m];
            int h = lane >> 3, d8 = lane & 7;
            const unsigned short* kb = KV + ((size_t)(l * 8 + h) << 20);
            const unsigned short* vb = KV + ((size_t)(16 + l * 8 + h) << 20);
            float av8[8], att8[8];
            {
                float4 u0 = *(const float4*)(&AV[SW32(r, lane * 8)]);
                float4 u1 = *(const float4*)(&AV[SW32(r, lane * 8 + 4)]);
                av8[0] = u0.x; av8[1] = u0.y; av8[2] = u0.z; av8[3] = u0.w;
                av8[4] = u1.x; av8[5] = u1.y; av8[6] = u1.z; av8[7] = u1.w;
            }
#pragma unroll
            for (int j = 0; j < 8; ++j) att8[j] = 0.f;
#pragma unroll 2
            for (int s = 0; s < 8; ++s) {
                int t1 = (s < iv) ? m : rt;
                size_t o0 = (size_t)((b * 8 + s) * 256 + lt) * 64 + d8 * 8;
                size_t o1 = (size_t)((b * 8 + s) * 256 + t1) * 64 + d8 * 8;
                uint4 k0u = *(const uint4*)(kb + o0);
                uint4 k1u = *(const uint4*)(kb + o1);
                uint4 v0u = *(const uint4*)(vb + o0);
                uint4 v1u = *(const uint4*)(vb + o1);
                const unsigned short* k0 = (const unsigned short*)&k0u;
                const unsigned short* k1 = (const unsigned short*)&k1u;
                const unsigned short* v0 = (const unsigned short*)&v0u;
                const unsigned short* v1 = (const unsigned short*)&v1u;
                float p0 = 0.f, p1 = 0.f;
#pragma unroll
                for (int j = 0; j < 8; ++j) {
                    p0 += av8[j] * bf2f(k0[j]);
                    p1 += av8[j] * bf2f(k1[j]);
                }
#pragma unroll
                for (int o = 1; o < 8; o <<= 1) {
                    p0 += __shfl_xor(p0, o, 64);
                    p1 += __shfl_xor(p1, o, 64);
                }
                p0 *= 0.125f; p1 *= 0.125f;
                float mx = fmaxf(p0, p1);
                float e0 = __expf(p0 - mx), e1 = __expf(p1 - mx);
                float inv = 1.f / (e0 + e1);
                float w0 = e0 * inv, w1 = e1 * inv;
#pragma unroll
                for (int j = 0; j < 8; ++j)
                    att8[j] += w0 * bf2f(v0[j]) + w1 * bf2f(v1[j]);
            }
            float x8[8], sum = 0.f;
#pragma unroll
            for (int j = 0; j < 8; ++j) { x8[j] = av8[j] + att8[j]; sum += x8[j]; }
            float mu = wred(sum) * (1.f / 512.f);
            float s2 = 0.f;
#pragma unroll
            for (int j = 0; j < 8; ++j) { float d = x8[j] - mu; s2 += d * d; }
            float rs = rsqrtf(wred(s2) * (1.f / 512.f) + 1e-5f);
            const float* gp = g1 + lane * 8;
            const float* bp = bb1 + lane * 8;
            __align__(16) float vout[8];
#pragma unroll
            for (int j = 0; j < 8; ++j) vout[j] = (x8[j] - mu) * rs * gp[j] + bp[j];
            *(float4*)(&XW[SW32(r, lane * 8)]) = *(float4*)vout;
            *(float4*)(&XW[SW32(r, lane * 8 + 4)]) = *(float4*)(vout + 4);
        }
        __syncthreads();

        // -- Phase 2: FF1 (A from XW, cvt on the fly) -> F1 bf16 (destroys AV)
        {
            f32x4 acc[4];
#pragma unroll
            for (int i = 0; i < 4; ++i) acc[i] = (f32x4){0.f, 0.f, 0.f, 0.f};
            short8 bw[4];
#pragma unroll
            for (int nt = 0; nt < 4; ++nt)
                bw[nt] = *(const short8*)(Wf1 + (size_t)((wave * 4 + nt) * 64 + lane) * 8);
            for (int kc = 0; kc < 16; ++kc) {
                short8 bwn[4];
                if (kc + 1 < 16) {
#pragma unroll
                    for (int nt = 0; nt < 4; ++nt)
                        bwn[nt] = *(const short8*)(Wf1 + (size_t)(((kc + 1) * 32 + wave * 4 + nt) * 64 + lane) * 8);
                }
                float4 u0 = *(const float4*)(&XW[SW32(id, kc * 32 + quad * 8)]);
                float4 u1 = *(const float4*)(&XW[SW32(id, kc * 32 + quad * 8 + 4)]);
                short8 a0;
                a0[0] = (short)f2bf(u0.x); a0[1] = (short)f2bf(u0.y); a0[2] = (short)f2bf(u0.z); a0[3] = (short)f2bf(u0.w);
                a0[4] = (short)f2bf(u1.x); a0[5] = (short)f2bf(u1.y); a0[6] = (short)f2bf(u1.z); a0[7] = (short)f2bf(u1.w);
#pragma unroll
                for (int nt = 0; nt < 4; ++nt)
                    acc[nt] = __builtin_amdgcn_mfma_f32_16x16x32_bf16(a0, bw[nt], acc[nt], 0, 0, 0);
#pragma unroll
                for (int nt = 0; nt < 4; ++nt) bw[nt] = bwn[nt];
            }
            __syncthreads();   // AV reads (ph1) done block-wide before F1 writes
#pragma unroll
            for (int nt = 0; nt < 4; ++nt) {
                int n0 = (wave * 4 + nt) * 16;
                float bv = fb1[n0 + id];
#pragma unroll
                for (int r = 0; r < 4; ++r)
                    F1[(quad * 4 + r) * 520 + n0 + id] = f2bf(fmaxf(acc[nt][r] + bv, 0.f));
            }
        }
        __syncthreads();

        // -- Phase 3: FF2 (A from F1) + bias + residual into XW in-place
        {
            f32x4 acc[4];
#pragma unroll
            for (int i = 0; i < 4; ++i) acc[i] = (f32x4){0.f, 0.f, 0.f, 0.f};
            short8 bw[4], a0;
#pragma unroll
            for (int nt = 0; nt < 4; ++nt)
                bw[nt] = *(const short8*)(Wf2 + (size_t)((wave * 4 + nt) * 64 + lane) * 8);
            a0 = *(const short8*)(&F1[id * 520 + quad * 8]);
            for (int kc = 0; kc < 16; ++kc) {
                short8 bwn[4], a0n;
                if (kc + 1 < 16) {
#pragma unroll
                    for (int nt = 0; nt < 4; ++nt)
                        bwn[nt] = *(const short8*)(Wf2 + (size_t)(((kc + 1) * 32 + wave * 4 + nt) * 64 + lane) * 8);
                    a0n = *(const short8*)(&F1[id * 520 + (kc + 1) * 32 + quad * 8]);
                }
#pragma unroll
                for (int nt = 0; nt < 4; ++nt)
                    acc[nt] = __builtin_amdgcn_mfma_f32_16x16x32_bf16(a0, bw[nt], acc[nt], 0, 0, 0);
#pragma unroll
                for (int nt = 0; nt < 4; ++nt) bw[nt] = bwn[nt];
                a0 = a0n;
            }
#pragma unroll
            for (int nt = 0; nt < 4; ++nt) {
                int n0 = (wave * 4 + nt) * 16;
                float bv = fb2[n0 + id];
#pragma unroll
                for (int r = 0; r < 4; ++r)
                    XW[SW32(quad * 4 + r, n0 + id)] += acc[nt][r] + bv;   // x + ff
            }
        }
        __syncthreads();

        // -- Phase 4: LN2; l==0 -> AV (f32, next layer); l==1 -> XD (bf16)
#pragma unroll
        for (int rr = 0; rr < 2; ++rr) {
            int r = wave * 2 + rr;
            float x8[8];
            {
                float4 u0 = *(const float4*)(&XW[SW32(r, lane * 8)]);
                float4 u1 = *(const float4*)(&XW[SW32(r, lane * 8 + 4)]);
                x8[0] = u0.x; x8[1] = u0.y; x8[2] = u0.z; x8[3] = u0.w;
                x8[4] = u1.x; x8[5] = u1.y; x8[6] = u1.z; x8[7] = u1.w;
            }
            float sum = 0.f;
#pragma unroll
            for (int j = 0; j < 8; ++j) sum += x8[j];
            float mu = wred(sum) * (1.f / 512.f);
            float s2 = 0.f;
#pragma unroll
            for (int j = 0; j < 8; ++j) { float d = x8[j] - mu; s2 += d * d; }
            float rs = rsqrtf(wred(s2) * (1.f / 512.f) + 1e-5f);
            const float* gp = g2 + lane * 8;
            const float* bp = bb2 + lane * 8;
            __align__(16) float vout[8];
#pragma unroll
            for (int j = 0; j < 8; ++j) vout[j] = (x8[j] - mu) * rs * gp[j] + bp[j];
            if (l == 0) {
                *(float4*)(&AV[SW32(r, lane * 8)]) = *(float4*)vout;
                *(float4*)(&AV[SW32(r, lane * 8 + 4)]) = *(float4*)(vout + 4);
            } else {
                __align__(16) unsigned short pb[8];
#pragma unroll
                for (int j = 0; j < 8; ++j) pb[j] = f2bf(vout[j]);
                *(uint4*)(&XD[r * 520 + lane * 8]) = *(uint4*)pb;
            }
        }
        __syncthreads();
    }

    // ---- Decoder: de1(relu) -> de2(relu) -> de3
    {
        f32x4 acc[2];
        acc[0] = (f32x4){0.f, 0.f, 0.f, 0.f};
        acc[1] = (f32x4){0.f, 0.f, 0.f, 0.f};
        short8 bw[2], a0;
#pragma unroll
        for (int nt = 0; nt < 2; ++nt)
            bw[nt] = *(const short8*)(Wde1 + (size_t)((wave * 2 + nt) * 64 + lane) * 8);
        a0 = *(const short8*)(&XD[id * 520 + quad * 8]);
        for (int kc = 0; kc < 16; ++kc) {
            short8 bwn[2], a0n;
            if (kc + 1 < 16) {
#pragma unroll
                for (int nt = 0; nt < 2; ++nt)
                    bwn[nt] = *(const short8*)(Wde1 + (size_t)(((kc + 1) * 16 + wave * 2 + nt) * 64 + lane) * 8);
                a0n = *(const short8*)(&XD[id * 520 + (kc + 1) * 32 + quad * 8]);
            }
#pragma unroll
            for (int nt = 0; nt < 2; ++nt)
                acc[nt] = __builtin_amdgcn_mfma_f32_16x16x32_bf16(a0, bw[nt], acc[nt], 0, 0, 0);
#pragma unroll
            for (int nt = 0; nt < 2; ++nt) bw[nt] = bwn[nt];
            a0 = a0n;
        }
        __syncthreads();   // XD fully read before D1 (XW region) writes
#pragma unroll
        for (int nt = 0; nt < 2; ++nt) {
            int n0 = (wave * 2 + nt) * 16;
            float bv = deb1[n0 + id];
#pragma unroll
            for (int r = 0; r < 4; ++r)
                D1[(quad * 4 + r) * 264 + n0 + id] = f2bf(fmaxf(acc[nt][r] + bv, 0.f));
        }
    }
    __syncthreads();
    {
        f32x4 acc[2];
        acc[0] = (f32x4){0.f, 0.f, 0.f, 0.f};
        acc[1] = (f32x4){0.f, 0.f, 0.f, 0.f};
        for (int kc = 0; kc < 8; ++kc) {
            short8 a0 = *(const short8*)(&D1[id * 264 + kc * 32 + quad * 8]);
#pragma unroll
            for (int nt = 0; nt < 2; ++nt) {
                short8 bw = *(const short8*)(Wde2 + (size_t)((kc * 16 + wave * 2 + nt) * 64 + lane) * 8);
                acc[nt] = __builtin_amdgcn_mfma_f32_16x16x32_bf16(a0, bw, acc[nt], 0, 0, 0);
            }
        }
#pragma unroll
        for (int nt = 0; nt < 2; ++nt) {
            int n0 = (wave * 2 + nt) * 16;
            float bv = deb2[n0 + id];
#pragma unroll
            for (int r = 0; r < 4; ++r)
                D2[(quad * 4 + r) * 264 + n0 + id] = f2bf(fmaxf(acc[nt][r] + bv, 0.f));
        }
    }
    __syncthreads();
    {
        f32x4 acc[4];
#pragma unroll
        for (int i = 0; i < 4; ++i) acc[i] = (f32x4){0.f, 0.f, 0.f, 0.f};
        for (int kc = 0; kc < 8; ++kc) {
            short8 a0 = *(const short8*)(&D2[id * 264 + kc * 32 + quad * 8]);
#pragma unroll
            for (int nt = 0; nt < 4; ++nt) {
                short8 bw = *(const short8*)(Wde3 + (size_t)((kc * 32 + wave * 4 + nt) * 64 + lane) * 8);
                acc[nt] = __builtin_amdgcn_mfma_f32_16x16x32_bf16(a0, bw, acc[nt], 0, 0, 0);
            }
        }
#pragma unroll
        for (int nt = 0; nt < 4; ++nt) {
            int n0 = (wave * 4 + nt) * 16;
            float bv = deb3[n0 + id];
#pragma unroll
            for (int r = 0; r < 4; ++r)
                out[(size_t)(m0 + quad * 4 + r) * 512 + n0 + id] = acc[nt][r] + bv;
        }
    }
}

// ---------------------------------------------------------------------------
extern "C" void kernel_launch(void* const* d_in, const int* in_sizes, int n_in,
                              void* d_out, int out_size, void* d_ws, size_t ws_size,
                              hipStream_t stream) {
    const float* encoded = (const float*)d_in[0];
    const float* true_u  = (const float*)d_in[1];
    const int* mid_idx   = (const int*)d_in[2];
    const int* left_idx  = (const int*)d_in[3];
    const int* right_idx = (const int*)d_in[4];
    const int* ip        = (const int*)d_in[5];
    const float* ds_W = (const float*)d_in[6];
    const float* ds_b = (const float*)d_in[7];
    const float* kW1 = (const float*)d_in[8];
    const float* kb1 = (const float*)d_in[9];
    const float* kW2 = (const float*)d_in[10];
    const float* kb2 = (const float*)d_in[11];
    const float* kW3 = (const float*)d_in[12];
    const float* kb3 = (const float*)d_in[13];
    const float* vW1 = (const float*)d_in[14];
    const float* vb1 = (const float*)d_in[15];
    const float* vW2 = (const float*)d_in[16];
    const float* vb2 = (const float*)d_in[17];
    const float* vW3 = (const float*)d_in[18];
    const float* vb3 = (const float*)d_in[19];
    const float* ln1_g = (const float*)d_in[20];
    const float* ln1_b = (const float*)d_in[21];
    const float* ln2_g = (const float*)d_in[22];
    const float* ln2_b = (const float*)d_in[23];
    const float* ffW1 = (const float*)d_in[24];
    const float* ffb1 = (const float*)d_in[25];
    const float* ffW2 = (const float*)d_in[26];
    const float* ffb2 = (const float*)d_in[27];
    const float* deW1 = (const float*)d_in[28];
    const float* deb1 = (const float*)d_in[29];
    const float* deW2 = (const float*)d_in[30];
    const float* deb2 = (const float*)d_in[31];
    const float* deW3 = (const float*)d_in[32];
    const float* deb3 = (const float*)d_in[33];

    char* ws = (char*)d_ws;
    unsigned short* XF    = (unsigned short*)(ws + 0);          //  8,388,608
    unsigned short* WP    = (unsigned short*)(ws + 8388608);    //  9,437,184
    float* W1L            = (float*)(ws + 17825792);            //     32,768
    unsigned short* KV    = (unsigned short*)(ws + 17858560);   // 67,108,864
    unsigned short* WG    = (unsigned short*)(ws + 84967424);   //  3,014,656

    // WG image offsets (halves)
    unsigned short* WGds    = WG + 0;
    unsigned short* WGff1_0 = WG + 131072;
    unsigned short* WGff1_1 = WG + 393216;
    unsigned short* WGff2_0 = WG + 655360;
    unsigned short* WGff2_1 = WG + 917504;
    unsigned short* WGde1   = WG + 1179648;
    unsigned short* WGde2   = WG + 1310720;
    unsigned short* WGde3   = WG + 1376256;

    prep_all<<<1648, 256, 0, stream>>>(encoded, kW1, kW2, kW3, vW1, vW2, vW3,
                                       ds_W, ffW1, ffW2, deW1, deW2, deW3,
                                       XF, WP, W1L, WG);
    heads_mlp<<<4096, 512, 0, stream>>>(true_u, XF, WP, W1L, kb1, kb2, kb3,
                                        vb1, vb2, vb3, KV);
    tail_fused<<<64, 512, 0, stream>>>(encoded, mid_idx, ip, WGds, ds_b, KV,
                                       left_idx, right_idx,
                                       ln1_g, ln1_b, ln2_g, ln2_b,
                                       WGff1_0, WGff1_1, ffb1,
                                       WGff2_0, WGff2_1, ffb2,
                                       WGde1, deb1, WGde2, deb2, WGde3, deb3,
                                       (float*)d_out);
}